// Round 2
// baseline (397.102 us; speedup 1.0000x reference)
//
#include <hip/hip_runtime.h>
#include <hip/hip_fp16.h>

// Problem constants (from reference)
#define N0C 4096
#define E0C 16384
#define N1C 1024
#define E1C 8192
#define HC 64
#define FINC 8
#define LATC 32
#define FC 67
#define E0T (E0C + N0C)
#define E1T (E1C + N1C)
#define GBLK 512   // 512 blocks @ (256,3) -> capacity 768, co-residency guaranteed

typedef float f32x4 __attribute__((ext_vector_type(4)));
typedef _Float16 f16x8 __attribute__((ext_vector_type(8)));

union SharedU {
  struct { float w2s[64][69]; float xr[4][64]; } prep;   // 18.7 KB
  struct {
    _Float16 bCs[4096], bSs[4096];
    _Float16 scS[4][2][64], scC[4][2][64];
  } conv;                                                 // 18.4 KB
};

// Device-scope grid barrier: monotonic counter, release-add + acquire-spin.
// RELEASE fetch_add -> waitcnt + L2 writeback (plain stores visible);
// ACQUIRE load -> L1/L2 invalidate (fresh reads). Thread 0 per block spins.
__device__ __forceinline__ void gsync(unsigned* bar, unsigned target) {
  __syncthreads();
  if (threadIdx.x == 0) {
    __hip_atomic_fetch_add(bar, 1u, __ATOMIC_RELEASE, __HIP_MEMORY_SCOPE_AGENT);
    while (__hip_atomic_load(bar, __ATOMIC_ACQUIRE, __HIP_MEMORY_SCOPE_AGENT) < target)
      __builtin_amdgcn_s_sleep(1);
  }
  __syncthreads();
}

// ---- conv phase: persistent edge-parallel, pipelined; atomicAdd scatter -----
__device__ __forceinline__ void conv_phase(
    SharedU& sh, const int* __restrict__ ei, int E, int eTot,
    const float* __restrict__ posp, const float* __restrict__ tN,
    const float* __restrict__ dN, const float* __restrict__ kw0,
    const float* __restrict__ kb0, const _Float16* __restrict__ bC,
    const _Float16* __restrict__ bS, const _Float16* __restrict__ w1f,
    const float* __restrict__ b1, float* __restrict__ acc_out) {
  const int tid = threadIdx.x;
  const int wave = __builtin_amdgcn_readfirstlane(tid >> 6), lane = tid & 63;
  const int q = lane >> 4;
  auto& cs = sh.conv;
  for (int idx = tid; idx < 512; idx += 256) {
    ((f16x8*)cs.bCs)[idx] = ((const f16x8*)bC)[idx];
    ((f16x8*)cs.bSs)[idx] = ((const f16x8*)bS)[idx];
  }
  f16x8 w1r[8];
#pragma unroll
  for (int f = 0; f < 8; ++f) w1r[f] = *(const f16x8*)(w1f + ((f << 6) + lane) * 8);
  f32x4 bbq[4];  // accumulator init = 0.1*b1[k]
#pragma unroll
  for (int ms = 0; ms < 4; ++ms) {
    f32x4 t = *(const f32x4*)(b1 + ms * 16 + q * 4);
    bbq[ms] = t * 0.1f;
  }
  const float kb0v = kb0[lane];
  const float kw0x = kw0[lane], kw0y = kw0[HC + lane], kw0z = kw0[2 * HC + lane];
  __syncthreads();

  const int nW = gridDim.x * 4;
  int e = blockIdx.x * 4 + wave;
  // e0 <= 2047 < eTot always: every wave has work (branch uniform-true)
  if (e < eTot) {
    auto stg = [&](int ee, int& sN, int& dTo, float& sv, float& cv, float& dv) {
      int s, d2;
      if (ee < E) { s = ei[ee]; d2 = ei[E + ee]; } else { s = ee - E; d2 = s; }
      sN = s;
      dTo = d2;
      const float px = posp[s * 3], py = posp[s * 3 + 1], pz = posp[s * 3 + 2];
      const float rx = posp[d2 * 3] - px;
      const float ry = posp[d2 * 3 + 1] - py;
      const float rz = posp[d2 * 3 + 2] - pz;
      float f0 = 0.f, f1 = 0.f, f2 = 0.f;
      if (!(rx == 0.f && ry == 0.f && rz == 0.f)) {
        const float PI_F = 3.14159265358979323846f;
        float rho = sqrtf(rx * rx + ry * ry + rz * rz);
        float th = atan2f(ry, rx);
        float ratio = fminf(1.f, fmaxf(-1.f, rz / rho));
        float ph = asinf(ratio);
        f0 = rho; f1 = th / PI_F; f2 = ph / PI_F;
      }
      float base = fmaf(f0, kw0x, fmaf(f1, kw0y, fmaf(f2, kw0z, kb0v)));
      // sv/cv rounded to f16 right after -> hw-sin error invisible
      __sincosf(0.1f * base, &sv, &cv);
      dv = dN[s];
    };

    int s0, d0;
    float sv0, cv0, dv0;
    stg(e, s0, d0, sv0, cv0, dv0);
    int buf = 0;
    cs.scS[wave][0][lane] = (_Float16)sv0;
    cs.scC[wave][0][lane] = (_Float16)cv0;
    __builtin_amdgcn_wave_barrier();

    while (true) {
      const int en = e + nW;
      const bool more = en < eTot;
      f32x4 tr[4];
      {
        const float* trp = tN + (size_t)s0 * HC;
#pragma unroll
        for (int ms = 0; ms < 4; ++ms) tr[ms] = *(const f32x4*)(trp + ms * 16 + q * 4);
      }
      int s1 = 0, d1 = 0;
      float sv1 = 0.f, cv1 = 0.f, dv1 = 0.f;
      if (more) {
        stg(en, s1, d1, sv1, cv1, dv1);
        cs.scS[wave][buf ^ 1][lane] = (_Float16)sv1;
        cs.scC[wave][buf ^ 1][lane] = (_Float16)cv1;
      }
      __builtin_amdgcn_wave_barrier();

      f32x4 acc[4][4];
#pragma unroll
      for (int ms = 0; ms < 4; ++ms)
#pragma unroll
        for (int nt = 0; nt < 4; ++nt) acc[ms][nt] = bbq[ms];
#pragma unroll
      for (int ks = 0; ks < 2; ++ks) {
        f16x8 sv8 = *(const f16x8*)&cs.scS[wave][buf][ks * 32 + q * 8];
        f16x8 cv8 = *(const f16x8*)&cs.scC[wave][buf][ks * 32 + q * 8];
        f16x8 bf[4];
#pragma unroll
        for (int nt = 0; nt < 4; ++nt) {
          f16x8 cb = *(const f16x8*)&cs.bCs[((ks * 4 + nt) * 64 + lane) * 8];
          f16x8 sb = *(const f16x8*)&cs.bSs[((ks * 4 + nt) * 64 + lane) * 8];
          bf[nt] = sv8 * cb + cv8 * sb;
        }
#pragma unroll
        for (int ms = 0; ms < 4; ++ms)
#pragma unroll
          for (int nt = 0; nt < 4; ++nt)
            acc[ms][nt] = __builtin_amdgcn_mfma_f32_16x16x32_f16(
                w1r[ks * 4 + ms], bf[nt], acc[ms][nt], 0, 0, 0);
      }

      float snt0 = 0.f, snt1 = 0.f, snt2 = 0.f, snt3 = 0.f;
#pragma unroll
      for (int ms = 0; ms < 4; ++ms) {
#pragma unroll
        for (int r = 0; r < 4; ++r) {
          float tt = tr[ms][r];
          snt0 = fmaf(__sinf(acc[ms][0][r]), tt, snt0);
          snt1 = fmaf(__sinf(acc[ms][1][r]), tt, snt1);
          snt2 = fmaf(__sinf(acc[ms][2][r]), tt, snt2);
          snt3 = fmaf(__sinf(acc[ms][3][r]), tt, snt3);
        }
      }
      snt0 += __shfl_xor(snt0, 16, 64); snt0 += __shfl_xor(snt0, 32, 64);
      snt1 += __shfl_xor(snt1, 16, 64); snt1 += __shfl_xor(snt1, 32, 64);
      snt2 += __shfl_xor(snt2, 16, 64); snt2 += __shfl_xor(snt2, 32, 64);
      snt3 += __shfl_xor(snt3, 16, 64); snt3 += __shfl_xor(snt3, 32, 64);
      float val = (q == 0) ? snt0 : (q == 1) ? snt1 : (q == 2) ? snt2 : snt3;
      atomicAdd(acc_out + (size_t)d0 * HC + lane, val + dv0);

      if (!more) break;
      e = en; s0 = s1; d0 = d1; dv0 = dv1; buf ^= 1;
    }
  }
}

// ---- the megakernel: all phases, 5 grid syncs -------------------------------
__global__ __launch_bounds__(256, 3) void k_mega(
    const float* __restrict__ x, const float* __restrict__ posp,
    const int* __restrict__ ei, const int* __restrict__ pei,
    const float* __restrict__ ppos, const int* __restrict__ keep,
    const float* __restrict__ l0w, const float* __restrict__ l0b,
    const float* __restrict__ l1w, const float* __restrict__ l1b,
    const float* __restrict__ c0w0, const float* __restrict__ c0b0,
    const float* __restrict__ c0w1, const float* __restrict__ c0b1,
    const float* __restrict__ c0w2, const float* __restrict__ c0b2,
    const float* __restrict__ c0bias,
    const float* __restrict__ c1w0, const float* __restrict__ c1b0,
    const float* __restrict__ c1w1, const float* __restrict__ c1b1,
    const float* __restrict__ c1w2, const float* __restrict__ c1b2,
    const float* __restrict__ c1bias,
    float* __restrict__ tN0, float* __restrict__ dN0,
    float* __restrict__ tN1, float* __restrict__ dN1,
    _Float16* __restrict__ bC0, _Float16* __restrict__ bS0,
    _Float16* __restrict__ bC1, _Float16* __restrict__ bS1,
    _Float16* __restrict__ w1f0, _Float16* __restrict__ w1f1,
    float* __restrict__ acc0, unsigned* __restrict__ pooled,
    float* __restrict__ acc1, unsigned* __restrict__ bar,
    float* __restrict__ outp) {
  __shared__ SharedU sh;
  const int tid = threadIdx.x;
  const int wave = __builtin_amdgcn_readfirstlane(tid >> 6), lane = tid & 63;
  const unsigned G = gridDim.x;

  // ---------------- phase 0: prep (encoder t/d, frags) + zero accumulators --
  if (blockIdx.x < 256) {
    for (int idx = tid; idx < HC * FC; idx += 256)
      sh.prep.w2s[idx / FC][idx % FC] = c0w2[idx];
    __syncthreads();
#pragma unroll
    for (int i = 0; i < 4; ++i) {
      const int n = (blockIdx.x * 4 + wave) + i * 1024;
      float a = l0b[lane];
#pragma unroll
      for (int f = 0; f < FINC; ++f) a = fmaf(x[n * FINC + f], l0w[f * HC + lane], a);
      sh.prep.xr[wave][lane] = sinf(0.01f * a);
      __builtin_amdgcn_wave_barrier();
      const float px = posp[n * 3], py = posp[n * 3 + 1], pz = posp[n * 3 + 2];
      float tl = 0.f, ds = 0.f;
#pragma unroll 8
      for (int f = 0; f < HC; ++f) {
        float xv = sh.prep.xr[wave][f];
        tl = fmaf(xv, sh.prep.w2s[lane][f], tl);
        ds = fmaf(xv, c0b2[f], ds);
      }
      tl = fmaf(px, sh.prep.w2s[lane][64],
           fmaf(py, sh.prep.w2s[lane][65], fmaf(pz, sh.prep.w2s[lane][66], tl)));
      ds = fmaf(px, c0b2[64], fmaf(py, c0b2[65], fmaf(pz, c0b2[66], ds)));
      tN0[n * HC + lane] = tl;
      if (lane == 0) dN0[n] = ds;
      __builtin_amdgcn_wave_barrier();
    }
  } else if (blockIdx.x < 320) {
    int id = (blockIdx.x - 256) * 256 + tid;
    if (id < 8192) {  // basis frags
      int lvl = id >> 12, r = id & 4095;
      int fi = r >> 9, ln = (r >> 3) & 63, j = r & 7;
      int nt = fi & 3, ks = fi >> 2;
      int c = nt * 16 + (ln & 15);
      int h = ks * 32 + (ln >> 4) * 8 + j;
      const float* w = lvl ? c1w0 : c0w0;
      float s, cv;
      sincosf(0.1f * (float)c * w[3 * HC + h], &s, &cv);
      (lvl ? bC1 : bC0)[r] = (_Float16)cv;
      (lvl ? bS1 : bS0)[r] = (_Float16)s;
    } else {  // w1 frags (pre-scaled by 0.1)
      int r0 = id - 8192;
      int lvl = r0 >> 12, r = r0 & 4095;
      int fi = r >> 9, ln = (r >> 3) & 63, j = r & 7;
      int ms = fi & 3, ks = fi >> 2;
      int h = ks * 32 + (ln >> 4) * 8 + j;
      int kout = ms * 16 + (ln & 15);
      const float* w = lvl ? c1w1 : c0w1;
      (lvl ? w1f1 : w1f0)[r] = (_Float16)(0.1f * w[h * HC + kout]);
    }
  } else {  // blocks 320..511: zero acc0|pooled|acc1 (contiguous, 2.25 MB)
    int t = (blockIdx.x - 320) * 256 + tid;  // 0..49151
    f32x4 z = {0.f, 0.f, 0.f, 0.f};
    f32x4* zp = (f32x4*)acc0;
    zp[t] = z;
    zp[t + 49152] = z;
    zp[t + 98304] = z;
  }
  gsync(bar, G * 1);

  // ---------------- phase 1: conv level 0 -----------------------------------
  conv_phase(sh, ei, E0C, E0T, posp, tN0, dN0, c0w0, c0b0, bC0, bS0, w1f0,
             c0b1, acc0);
  gsync(bar, G * 2);

  // ---------------- phase 2: edge-parallel max-pool -------------------------
  {
    const float bz = c0bias[lane];
    for (int e = blockIdx.x * 4 + wave; e < E0T; e += gridDim.x * 4) {
      int s, d;
      if (e < E0C) { s = ei[e]; d = ei[E0C + e]; } else { s = e - E0C; d = s; }
      float v = sinf(0.01f * (acc0[(size_t)s * HC + lane] + bz));
      unsigned b = __float_as_uint(v);
      unsigned key = (b & 0x80000000u) ? ~b : (b | 0x80000000u);
      atomicMax(pooled + (size_t)d * HC + lane, key);
    }
  }
  gsync(bar, G * 3);

  // ---------------- phase 3: decode pooled + t/d for level 1 ----------------
  if (blockIdx.x < 256) {
    for (int idx = tid; idx < HC * FC; idx += 256)
      sh.prep.w2s[idx / FC][idx % FC] = c1w2[idx];
    const int i = blockIdx.x * 4 + wave;
    const int n = keep[i];  // duplicate keep ids read the same node row: OK
    unsigned key = pooled[(size_t)n * HC + lane];
    unsigned b = (key & 0x80000000u) ? (key & 0x7FFFFFFFu) : ~key;
    sh.prep.xr[wave][lane] = __uint_as_float(b);
    __syncthreads();
    const float px = ppos[i * 3], py = ppos[i * 3 + 1], pz = ppos[i * 3 + 2];
    float tl = 0.f, ds = 0.f;
#pragma unroll 8
    for (int f = 0; f < HC; ++f) {
      float xv = sh.prep.xr[wave][f];
      tl = fmaf(xv, sh.prep.w2s[lane][f], tl);
      ds = fmaf(xv, c1b2[f], ds);
    }
    tl = fmaf(px, sh.prep.w2s[lane][64],
         fmaf(py, sh.prep.w2s[lane][65], fmaf(pz, sh.prep.w2s[lane][66], tl)));
    ds = fmaf(px, c1b2[64], fmaf(py, c1b2[65], fmaf(pz, c1b2[66], ds)));
    tN1[i * HC + lane] = tl;
    if (lane == 0) dN1[i] = ds;
  }
  gsync(bar, G * 4);

  // ---------------- phase 4: conv level 1 -----------------------------------
  conv_phase(sh, pei, E1C, E1T, ppos, tN1, dN1, c1w0, c1b0, bC1, bS1, w1f1,
             c1b1, acc1);
  gsync(bar, G * 5);

  // ---------------- phase 5: final linear + sin -----------------------------
  if (blockIdx.x < 256) {
    const int node = blockIdx.x * 4 + wave;
    sh.prep.xr[wave][lane] = sinf(0.01f * (acc1[(size_t)node * HC + lane] + c1bias[lane]));
    __syncthreads();
    if (lane < LATC) {
      const float* h = sh.prep.xr[wave];
      float o = l1b[lane];
#pragma unroll 8
      for (int c = 0; c < HC; ++c) o = fmaf(h[c], l1w[c * LATC + lane], o);
      outp[node * LATC + lane] = sinf(0.01f * o);
    }
  }
}

extern "C" void kernel_launch(void* const* d_in, const int* in_sizes, int n_in,
                              void* d_out, int out_size, void* d_ws, size_t ws_size,
                              hipStream_t stream) {
  (void)in_sizes; (void)n_in; (void)out_size; (void)ws_size;
  const float* x    = (const float*)d_in[0];
  const float* pos  = (const float*)d_in[1];
  const int*   ei   = (const int*)d_in[2];
  const int*   pei  = (const int*)d_in[3];
  const float* ppos = (const float*)d_in[4];
  const int*   keep = (const int*)d_in[5];
  const float* l0w  = (const float*)d_in[6];
  const float* l0b  = (const float*)d_in[7];
  const float* l1w  = (const float*)d_in[8];
  const float* l1b  = (const float*)d_in[9];
  const float* c0w0 = (const float*)d_in[10];
  const float* c0b0 = (const float*)d_in[11];
  const float* c0w1 = (const float*)d_in[12];
  const float* c0b1 = (const float*)d_in[13];
  const float* c0w2 = (const float*)d_in[14];
  const float* c0b2 = (const float*)d_in[15];
  const float* c0bias = (const float*)d_in[16];
  const float* c1w0 = (const float*)d_in[17];
  const float* c1b0 = (const float*)d_in[18];
  const float* c1w1 = (const float*)d_in[19];
  const float* c1b1 = (const float*)d_in[20];
  const float* c1w2 = (const float*)d_in[21];
  const float* c1b2 = (const float*)d_in[22];
  const float* c1bias = (const float*)d_in[23];
  float* outp = (float*)d_out;

  char* p = (char*)d_ws;
  auto carve = [&](size_t bytes) -> char* {
    char* r = p;
    p += (bytes + 255) & ~(size_t)255;
    return r;
  };
  float* tN0  = (float*)carve((size_t)N0C * HC * 4);
  float* dN0  = (float*)carve((size_t)N0C * 4);
  float* tN1  = (float*)carve((size_t)N1C * HC * 4);
  float* dN1  = (float*)carve((size_t)N1C * 4);
  _Float16* bC0  = (_Float16*)carve(4096 * 2);
  _Float16* bS0  = (_Float16*)carve(4096 * 2);
  _Float16* bC1  = (_Float16*)carve(4096 * 2);
  _Float16* bS1  = (_Float16*)carve(4096 * 2);
  _Float16* w1f0 = (_Float16*)carve(4096 * 2);
  _Float16* w1f1 = (_Float16*)carve(4096 * 2);
  // acc0 / pooled / acc1 contiguous (1MB | 1MB | 256KB): zeroed in phase 0
  float* acc0 = (float*)carve((size_t)N0C * HC * 4);
  unsigned* pooled = (unsigned*)carve((size_t)N0C * HC * 4);
  float* acc1 = (float*)carve((size_t)N1C * HC * 4);
  unsigned* bar = (unsigned*)carve(256);

  // workspace is poisoned between iterations -> barrier word must be re-zeroed
  hipMemsetAsync(bar, 0, 256, stream);

  k_mega<<<GBLK, 256, 0, stream>>>(
      x, pos, ei, pei, ppos, keep, l0w, l0b, l1w, l1b,
      c0w0, c0b0, c0w1, c0b1, c0w2, c0b2, c0bias,
      c1w0, c1b0, c1w1, c1b1, c1w2, c1b2, c1bias,
      tN0, dN0, tN1, dN1, bC0, bS0, bC1, bS1, w1f0, w1f1,
      acc0, pooled, acc1, bar, outp);
}

// Round 3
// 163.158 us; speedup vs baseline: 2.4339x; 2.4339x over previous
//
#include <hip/hip_runtime.h>
#include <hip/hip_fp16.h>

// Problem constants (from reference)
#define N0C 4096
#define E0C 16384
#define N1C 1024
#define E1C 8192
#define HC 64
#define FINC 8
#define LATC 32
#define FC 67
#define E0T (E0C + N0C)
#define E1T (E1C + N1C)

typedef float f32x4 __attribute__((ext_vector_type(4)));
typedef _Float16 f16x8 __attribute__((ext_vector_type(8)));

// ---- k_prep: blocks [0,256): encoder + per-node t/d (level 0, 4 nodes/wave)
//              blocks [256,320): basis+w1 frag packing (fp16)
//              blocks [320,512): zero acc0|pooled|acc1 (2.25 MB contiguous)
__global__ __launch_bounds__(256) void k_prep(
    const float* __restrict__ x, const float* __restrict__ l0w,
    const float* __restrict__ l0b, const float* __restrict__ posp,
    const float* __restrict__ c0w2, const float* __restrict__ c0b2,
    const float* __restrict__ c0w0, const float* __restrict__ c1w0,
    const float* __restrict__ c0w1, const float* __restrict__ c1w1,
    _Float16* __restrict__ bC0, _Float16* __restrict__ bS0,
    _Float16* __restrict__ bC1, _Float16* __restrict__ bS1,
    _Float16* __restrict__ w1f0, _Float16* __restrict__ w1f1,
    float* __restrict__ tN, float* __restrict__ dN,
    float* __restrict__ accz) {
  if (blockIdx.x < 256) {
    __shared__ float w2s[64][69];  // pad 67->69
    __shared__ float xr[4][64];
    const int tid = threadIdx.x;
    const int wave = __builtin_amdgcn_readfirstlane(tid >> 6), lane = tid & 63;
    for (int idx = tid; idx < HC * FC; idx += 256)
      w2s[idx / FC][idx % FC] = c0w2[idx];
    __syncthreads();
#pragma unroll
    for (int i = 0; i < 4; ++i) {
      const int n = (blockIdx.x * 4 + wave) + i * 1024;
      float a = l0b[lane];
#pragma unroll
      for (int f = 0; f < FINC; ++f) a = fmaf(x[n * FINC + f], l0w[f * HC + lane], a);
      xr[wave][lane] = sinf(0.01f * a);
      __builtin_amdgcn_wave_barrier();
      const float px = posp[n * 3], py = posp[n * 3 + 1], pz = posp[n * 3 + 2];
      float tl = 0.f, ds = 0.f;
#pragma unroll 8
      for (int f = 0; f < HC; ++f) {
        float xv = xr[wave][f];
        tl = fmaf(xv, w2s[lane][f], tl);
        ds = fmaf(xv, c0b2[f], ds);
      }
      tl = fmaf(px, w2s[lane][64], fmaf(py, w2s[lane][65], fmaf(pz, w2s[lane][66], tl)));
      ds = fmaf(px, c0b2[64], fmaf(py, c0b2[65], fmaf(pz, c0b2[66], ds)));
      tN[n * HC + lane] = tl;
      if (lane == 0) dN[n] = ds;
      __builtin_amdgcn_wave_barrier();
    }
  } else if (blockIdx.x < 320) {
    int id = (blockIdx.x - 256) * 256 + threadIdx.x;
    if (id < 8192) {  // basis frags: r=((ks*4+nt)*64+lane)*8+j
      int lvl = id >> 12, r = id & 4095;
      int fi = r >> 9, lane = (r >> 3) & 63, j = r & 7;
      int nt = fi & 3, ks = fi >> 2;
      int c = nt * 16 + (lane & 15);
      int h = ks * 32 + (lane >> 4) * 8 + j;
      const float* w = lvl ? c1w0 : c0w0;
      float s, cv;
      sincosf(0.1f * (float)c * w[3 * HC + h], &s, &cv);
      (lvl ? bC1 : bC0)[r] = (_Float16)cv;
      (lvl ? bS1 : bS0)[r] = (_Float16)s;
    } else {  // w1 frags (pre-scaled by 0.1)
      int r0 = id - 8192;
      int lvl = r0 >> 12, r = r0 & 4095;
      int fi = r >> 9, lane = (r >> 3) & 63, j = r & 7;
      int ms = fi & 3, ks = fi >> 2;
      int h = ks * 32 + (lane >> 4) * 8 + j;
      int kout = ms * 16 + (lane & 15);
      const float* w = lvl ? c1w1 : c0w1;
      (lvl ? w1f1 : w1f0)[r] = (_Float16)(0.1f * w[h * HC + kout]);
    }
  } else {  // zero acc0|pooled|acc1: 147456 f32x4 over 192*256 threads
    int t = (blockIdx.x - 320) * 256 + threadIdx.x;  // 0..49151
    f32x4 z = {0.f, 0.f, 0.f, 0.f};
    f32x4* zp = (f32x4*)accz;
    zp[t] = z;
    zp[t + 49152] = z;
    zp[t + 98304] = z;
  }
}

// ---- k_conv: persistent edge-parallel, pipelined; accumulates via atomicAdd -
// (256,3) = ~84 VGPR no spill, LDS cb/sb tables, 2-stage pipeline.
__global__ __launch_bounds__(256, 3) void k_conv(
    const int* __restrict__ ei, int E, int eTot,
    const float* __restrict__ posp,
    const float* __restrict__ tN, const float* __restrict__ dN,
    const float* __restrict__ kw0, const float* __restrict__ kb0,
    const _Float16* __restrict__ bC, const _Float16* __restrict__ bS,
    const _Float16* __restrict__ w1f, const float* __restrict__ b1,
    float* __restrict__ acc_out) {
  __shared__ __attribute__((aligned(16))) _Float16 bCs[4096], bSs[4096];
  __shared__ __attribute__((aligned(16))) _Float16 scS[4][2][64], scC[4][2][64];
  const int tid = threadIdx.x;
  const int wave = __builtin_amdgcn_readfirstlane(tid >> 6), lane = tid & 63;
  const int q = lane >> 4;
  for (int idx = tid; idx < 512; idx += 256) {
    ((f16x8*)bCs)[idx] = ((const f16x8*)bC)[idx];
    ((f16x8*)bSs)[idx] = ((const f16x8*)bS)[idx];
  }
  f16x8 w1r[8];
#pragma unroll
  for (int f = 0; f < 8; ++f) w1r[f] = *(const f16x8*)(w1f + ((f << 6) + lane) * 8);
  f32x4 bbq[4];  // accumulator init = 0.1*b1[k]
#pragma unroll
  for (int ms = 0; ms < 4; ++ms) {
    f32x4 t = *(const f32x4*)(b1 + ms * 16 + q * 4);
    bbq[ms] = t * 0.1f;
  }
  const float kb0v = kb0[lane];
  const float kw0x = kw0[lane], kw0y = kw0[HC + lane], kw0z = kw0[2 * HC + lane];
  __syncthreads();

  const int nW = gridDim.x * 4;
  int e = blockIdx.x * 4 + wave;
  if (e >= eTot) return;

  // Fast branchless trig: results feed sin(0.1*base) which is rounded to f16
  // (5e-4 rel ulp) -> poly errors (atan ~1e-7, asin ~7e-5 rad) are invisible.
  auto stg = [&](int ee, int& sN, int& dTo, float& sv, float& cv, float& dv) {
    int s, d2;
    if (ee < E) { s = ei[ee]; d2 = ei[E + ee]; } else { s = ee - E; d2 = s; }
    sN = s;
    dTo = d2;
    const float px = posp[s * 3], py = posp[s * 3 + 1], pz = posp[s * 3 + 2];
    const float rx = posp[d2 * 3] - px;
    const float ry = posp[d2 * 3 + 1] - py;
    const float rz = posp[d2 * 3 + 2] - pz;
    float f0 = 0.f, f1 = 0.f, f2 = 0.f;
    if (!(rx == 0.f && ry == 0.f && rz == 0.f)) {
      const float INV_PI = 0.3183098861837907f;
      const float PI_F = 3.14159265358979f;
      const float PI_2 = 1.5707963267948966f;
      float rho = sqrtf(rx * rx + ry * ry + rz * rz);
      // theta = atan2(ry,rx): octant reduction + odd minimax poly on [0,1]
      float ax = fabsf(rx), ay = fabsf(ry);
      float mx = fmaxf(ax, ay), mn = fminf(ax, ay);
      float zr = mn * __builtin_amdgcn_rcpf(mx);
      float z2 = zr * zr;
      float pa = fmaf(z2, -0.0040540580f, 0.0218612288f);
      pa = fmaf(z2, pa, -0.0559098861f);
      pa = fmaf(z2, pa, 0.0964200441f);
      pa = fmaf(z2, pa, -0.1390853351f);
      pa = fmaf(z2, pa, 0.1994653599f);
      pa = fmaf(z2, pa, -0.3332985605f);
      pa = fmaf(z2, pa, 0.9999993329f);
      float at = pa * zr;
      at = (ay > ax) ? (PI_2 - at) : at;
      at = (rx < 0.f) ? (PI_F - at) : at;
      float th = copysignf(at, ry);
      // phi = asin(clip(rz/rho)): A&S 4.4.45, err <= 7e-5 rad
      float zz = rz * __builtin_amdgcn_rcpf(rho);
      float az = fminf(fabsf(zz), 1.0f);
      float sq = sqrtf(1.0f - az);
      float pp = fmaf(az, -0.0187293f, 0.0742610f);
      pp = fmaf(az, pp, -0.2121144f);
      pp = fmaf(az, pp, 1.5707288f);
      float as = PI_2 - sq * pp;
      float ph = copysignf(as, zz);
      f0 = rho; f1 = th * INV_PI; f2 = ph * INV_PI;
    }
    float base = fmaf(f0, kw0x, fmaf(f1, kw0y, fmaf(f2, kw0z, kb0v)));
    __sincosf(0.1f * base, &sv, &cv);
    dv = dN[s];
  };

  int s0, d0;
  float sv0, cv0, dv0;
  stg(e, s0, d0, sv0, cv0, dv0);
  int buf = 0;
  scS[wave][0][lane] = (_Float16)sv0;
  scC[wave][0][lane] = (_Float16)cv0;
  __builtin_amdgcn_wave_barrier();

  while (true) {
    const int en = e + nW;
    const bool more = en < eTot;
    // prefetch t-row for current edge
    f32x4 tr[4];
    {
      const float* trp = tN + (size_t)s0 * HC;
#pragma unroll
      for (int ms = 0; ms < 4; ++ms) tr[ms] = *(const f32x4*)(trp + ms * 16 + q * 4);
    }
    // stage next edge (loads + trig) before compute of current
    int s1 = 0, d1 = 0;
    float sv1 = 0.f, cv1 = 0.f, dv1 = 0.f;
    if (more) {
      stg(en, s1, d1, sv1, cv1, dv1);
      scS[wave][buf ^ 1][lane] = (_Float16)sv1;
      scC[wave][buf ^ 1][lane] = (_Float16)cv1;
    }
    __builtin_amdgcn_wave_barrier();

    f32x4 acc[4][4];
#pragma unroll
    for (int ms = 0; ms < 4; ++ms)
#pragma unroll
      for (int nt = 0; nt < 4; ++nt) acc[ms][nt] = bbq[ms];
#pragma unroll
    for (int ks = 0; ks < 2; ++ks) {
      f16x8 sv8 = *(const f16x8*)&scS[wave][buf][ks * 32 + q * 8];
      f16x8 cv8 = *(const f16x8*)&scC[wave][buf][ks * 32 + q * 8];
      f16x8 bf[4];
#pragma unroll
      for (int nt = 0; nt < 4; ++nt) {
        f16x8 cb = *(const f16x8*)&bCs[((ks * 4 + nt) * 64 + lane) * 8];
        f16x8 sb = *(const f16x8*)&bSs[((ks * 4 + nt) * 64 + lane) * 8];
        bf[nt] = sv8 * cb + cv8 * sb;
      }
#pragma unroll
      for (int ms = 0; ms < 4; ++ms)
#pragma unroll
        for (int nt = 0; nt < 4; ++nt)
          acc[ms][nt] = __builtin_amdgcn_mfma_f32_16x16x32_f16(
              w1r[ks * 4 + ms], bf[nt], acc[ms][nt], 0, 0, 0);
    }

    // epilogue: reg r of acc[ms][nt] = 0.1*(z+b1) at [k=ms*16+q*4+r][c=nt*16+m]
    float snt0 = 0.f, snt1 = 0.f, snt2 = 0.f, snt3 = 0.f;
#pragma unroll
    for (int ms = 0; ms < 4; ++ms) {
#pragma unroll
      for (int r = 0; r < 4; ++r) {
        float tt = tr[ms][r];
        snt0 = fmaf(__sinf(acc[ms][0][r]), tt, snt0);
        snt1 = fmaf(__sinf(acc[ms][1][r]), tt, snt1);
        snt2 = fmaf(__sinf(acc[ms][2][r]), tt, snt2);
        snt3 = fmaf(__sinf(acc[ms][3][r]), tt, snt3);
      }
    }
    snt0 += __shfl_xor(snt0, 16, 64); snt0 += __shfl_xor(snt0, 32, 64);
    snt1 += __shfl_xor(snt1, 16, 64); snt1 += __shfl_xor(snt1, 32, 64);
    snt2 += __shfl_xor(snt2, 16, 64); snt2 += __shfl_xor(snt2, 32, 64);
    snt3 += __shfl_xor(snt3, 16, 64); snt3 += __shfl_xor(snt3, 32, 64);
    float val = (q == 0) ? snt0 : (q == 1) ? snt1 : (q == 2) ? snt2 : snt3;
    // direct scatter-accumulate: per-dst contention ~avg degree 5, acc is L2-resident
    atomicAdd(acc_out + (size_t)d0 * HC + lane, val + dv0);

    if (!more) break;
    e = en; s0 = s1; d0 = d1; dv0 = dv1; buf ^= 1;
  }
}

// ---- k_pool: edge-parallel max-pool of sin(0.01*(acc0[src]+bias)) into
//      per-NODE pooled buffer (order-preserving uint encoding; zeroed init:
//      every real value encodes >= 0x007FFFFF, every node has a self loop).
__global__ __launch_bounds__(256) void k_pool(
    const int* __restrict__ ei, const float* __restrict__ acc0,
    const float* __restrict__ bias, unsigned int* __restrict__ pooled) {
  const int wave = threadIdx.x >> 6, lane = threadIdx.x & 63;
  const float bz = bias[lane];
  for (int e = blockIdx.x * 4 + wave; e < E0T; e += gridDim.x * 4) {
    int s, d;
    if (e < E0C) { s = ei[e]; d = ei[E0C + e]; } else { s = e - E0C; d = s; }
    float v = sinf(0.01f * (acc0[(size_t)s * HC + lane] + bz));
    unsigned int b = __float_as_uint(v);
    unsigned int key = (b & 0x80000000u) ? ~b : (b | 0x80000000u);
    atomicMax(pooled + (size_t)d * HC + lane, key);
  }
}

// ---- k_t1: decode pooled rows for kept nodes + per-node t/d for level 1 -----
__global__ __launch_bounds__(256) void k_t1(
    const unsigned int* __restrict__ pooled, const int* __restrict__ keep,
    const float* __restrict__ ppos, const float* __restrict__ c1w2,
    const float* __restrict__ c1b2, float* __restrict__ tN, float* __restrict__ dN) {
  __shared__ float w2s[64][69];
  __shared__ float xr[4][64];
  const int tid = threadIdx.x;
  const int wave = __builtin_amdgcn_readfirstlane(tid >> 6), lane = tid & 63;
  for (int idx = tid; idx < HC * FC; idx += 256)
    w2s[idx / FC][idx % FC] = c1w2[idx];
  const int i = blockIdx.x * 4 + wave;
  const int n = keep[i];  // duplicates in keep read the same node row: correct
  unsigned int key = pooled[(size_t)n * HC + lane];
  unsigned int b = (key & 0x80000000u) ? (key & 0x7FFFFFFFu) : ~key;
  xr[wave][lane] = __uint_as_float(b);
  __syncthreads();
  const float px = ppos[i * 3], py = ppos[i * 3 + 1], pz = ppos[i * 3 + 2];
  float tl = 0.f, ds = 0.f;
#pragma unroll 8
  for (int f = 0; f < HC; ++f) {
    float xv = xr[wave][f];
    tl = fmaf(xv, w2s[lane][f], tl);
    ds = fmaf(xv, c1b2[f], ds);
  }
  tl = fmaf(px, w2s[lane][64], fmaf(py, w2s[lane][65], fmaf(pz, w2s[lane][66], tl)));
  ds = fmaf(px, c1b2[64], fmaf(py, c1b2[65], fmaf(pz, c1b2[66], ds)));
  tN[i * HC + lane] = tl;
  if (lane == 0) dN[i] = ds;
}

// ---- k_final: sin(0.01*(acc1+bias)) + final linear + sin --------------------
__global__ __launch_bounds__(256) void k_final(
    const float* __restrict__ acc1, const float* __restrict__ bias,
    const float* __restrict__ l1w, const float* __restrict__ l1b,
    float* __restrict__ outp) {
  __shared__ float hr[4][64];
  const int wave = threadIdx.x >> 6, lane = threadIdx.x & 63;
  const int node = blockIdx.x * 4 + wave;
  hr[wave][lane] = sinf(0.01f * (acc1[(size_t)node * HC + lane] + bias[lane]));
  __syncthreads();
  if (lane < LATC) {
    const float* h = hr[wave];
    float o = l1b[lane];
#pragma unroll 8
    for (int c = 0; c < HC; ++c) o = fmaf(h[c], l1w[c * LATC + lane], o);
    outp[node * LATC + lane] = sinf(0.01f * o);
  }
}

extern "C" void kernel_launch(void* const* d_in, const int* in_sizes, int n_in,
                              void* d_out, int out_size, void* d_ws, size_t ws_size,
                              hipStream_t stream) {
  (void)in_sizes; (void)n_in; (void)out_size; (void)ws_size;
  const float* x    = (const float*)d_in[0];
  const float* pos  = (const float*)d_in[1];
  const int*   ei   = (const int*)d_in[2];
  const int*   pei  = (const int*)d_in[3];
  const float* ppos = (const float*)d_in[4];
  const int*   keep = (const int*)d_in[5];
  const float* l0w  = (const float*)d_in[6];
  const float* l0b  = (const float*)d_in[7];
  const float* l1w  = (const float*)d_in[8];
  const float* l1b  = (const float*)d_in[9];
  const float* c0w0 = (const float*)d_in[10];
  const float* c0b0 = (const float*)d_in[11];
  const float* c0w1 = (const float*)d_in[12];
  const float* c0b1 = (const float*)d_in[13];
  const float* c0w2 = (const float*)d_in[14];
  const float* c0b2 = (const float*)d_in[15];
  const float* c0bias = (const float*)d_in[16];
  const float* c1w0 = (const float*)d_in[17];
  const float* c1b0 = (const float*)d_in[18];
  const float* c1w1 = (const float*)d_in[19];
  const float* c1b1 = (const float*)d_in[20];
  const float* c1w2 = (const float*)d_in[21];
  const float* c1b2 = (const float*)d_in[22];
  const float* c1bias = (const float*)d_in[23];
  float* outp = (float*)d_out;

  char* p = (char*)d_ws;
  auto carve = [&](size_t bytes) -> char* {
    char* r = p;
    p += (bytes + 255) & ~(size_t)255;
    return r;
  };
  float* tN0  = (float*)carve((size_t)N0C * HC * 4);
  float* dN0  = (float*)carve((size_t)N0C * 4);
  float* tN1  = (float*)carve((size_t)N1C * HC * 4);
  float* dN1  = (float*)carve((size_t)N1C * 4);
  _Float16* bC0  = (_Float16*)carve(4096 * 2);
  _Float16* bS0  = (_Float16*)carve(4096 * 2);
  _Float16* bC1  = (_Float16*)carve(4096 * 2);
  _Float16* bS1  = (_Float16*)carve(4096 * 2);
  _Float16* w1f0 = (_Float16*)carve(4096 * 2);
  _Float16* w1f1 = (_Float16*)carve(4096 * 2);
  // acc0 / pooled / acc1 contiguous (1MB | 1MB | 256KB): zeroed in k_prep
  float* acc0 = (float*)carve((size_t)N0C * HC * 4);
  unsigned int* pooled = (unsigned int*)carve((size_t)N0C * HC * 4);
  float* acc1 = (float*)carve((size_t)N1C * HC * 4);

  k_prep<<<512, 256, 0, stream>>>(x, l0w, l0b, pos, c0w2, c0b2,
                                  c0w0, c1w0, c0w1, c1w1,
                                  bC0, bS0, bC1, bS1, w1f0, w1f1,
                                  tN0, dN0, acc0);
  k_conv<<<1536, 256, 0, stream>>>(ei, E0C, E0T, pos, tN0, dN0, c0w0, c0b0,
                                   bC0, bS0, w1f0, c0b1, acc0);
  k_pool<<<1280, 256, 0, stream>>>(ei, acc0, c0bias, pooled);
  k_t1<<<N1C / 4, 256, 0, stream>>>(pooled, keep, ppos, c1w2, c1b2, tN1, dN1);
  k_conv<<<768, 256, 0, stream>>>(pei, E1C, E1T, ppos, tN1, dN1, c1w0, c1b0,
                                  bC1, bS1, w1f1, c1b1, acc1);
  k_final<<<N1C / 4, 256, 0, stream>>>(acc1, c1bias, l1w, l1b, outp);
}

// Round 4
// 162.475 us; speedup vs baseline: 2.4441x; 1.0042x over previous
//
#include <hip/hip_runtime.h>
#include <hip/hip_fp16.h>

// Problem constants (from reference)
#define N0C 4096
#define E0C 16384
#define N1C 1024
#define E1C 8192
#define HC 64
#define FINC 8
#define LATC 32
#define FC 67
#define E0T (E0C + N0C)
#define E1T (E1C + N1C)

typedef float f32x4 __attribute__((ext_vector_type(4)));
typedef _Float16 f16x8 __attribute__((ext_vector_type(8)));

// ---- k_prep: blocks [0,256): encoder + per-node t/d (level 0, 4 nodes/wave)
//              blocks [256,320): basis+w1 frag packing (fp16)
//              blocks [320,512): zero acc0|pooled|acc1 (2.25 MB contiguous)
__global__ __launch_bounds__(256) void k_prep(
    const float* __restrict__ x, const float* __restrict__ l0w,
    const float* __restrict__ l0b, const float* __restrict__ posp,
    const float* __restrict__ c0w2, const float* __restrict__ c0b2,
    const float* __restrict__ c0w0, const float* __restrict__ c1w0,
    const float* __restrict__ c0w1, const float* __restrict__ c1w1,
    _Float16* __restrict__ bC0, _Float16* __restrict__ bS0,
    _Float16* __restrict__ bC1, _Float16* __restrict__ bS1,
    _Float16* __restrict__ w1f0, _Float16* __restrict__ w1f1,
    float* __restrict__ tN, float* __restrict__ dN,
    float* __restrict__ accz) {
  if (blockIdx.x < 256) {
    __shared__ float w2s[64][69];  // pad 67->69
    __shared__ float xr[4][64];
    const int tid = threadIdx.x;
    const int wave = __builtin_amdgcn_readfirstlane(tid >> 6), lane = tid & 63;
    for (int idx = tid; idx < HC * FC; idx += 256)
      w2s[idx / FC][idx % FC] = c0w2[idx];
    __syncthreads();
#pragma unroll
    for (int i = 0; i < 4; ++i) {
      const int n = (blockIdx.x * 4 + wave) + i * 1024;
      float a = l0b[lane];
#pragma unroll
      for (int f = 0; f < FINC; ++f) a = fmaf(x[n * FINC + f], l0w[f * HC + lane], a);
      xr[wave][lane] = sinf(0.01f * a);
      __builtin_amdgcn_wave_barrier();
      const float px = posp[n * 3], py = posp[n * 3 + 1], pz = posp[n * 3 + 2];
      float tl = 0.f, ds = 0.f;
#pragma unroll 8
      for (int f = 0; f < HC; ++f) {
        float xv = xr[wave][f];
        tl = fmaf(xv, w2s[lane][f], tl);
        ds = fmaf(xv, c0b2[f], ds);
      }
      tl = fmaf(px, w2s[lane][64], fmaf(py, w2s[lane][65], fmaf(pz, w2s[lane][66], tl)));
      ds = fmaf(px, c0b2[64], fmaf(py, c0b2[65], fmaf(pz, c0b2[66], ds)));
      tN[n * HC + lane] = tl;
      if (lane == 0) dN[n] = ds;
      __builtin_amdgcn_wave_barrier();
    }
  } else if (blockIdx.x < 320) {
    int id = (blockIdx.x - 256) * 256 + threadIdx.x;
    if (id < 8192) {  // basis frags: r=((ks*4+nt)*64+lane)*8+j
      int lvl = id >> 12, r = id & 4095;
      int fi = r >> 9, lane = (r >> 3) & 63, j = r & 7;
      int nt = fi & 3, ks = fi >> 2;
      int c = nt * 16 + (lane & 15);
      int h = ks * 32 + (lane >> 4) * 8 + j;
      const float* w = lvl ? c1w0 : c0w0;
      float s, cv;
      sincosf(0.1f * (float)c * w[3 * HC + h], &s, &cv);
      (lvl ? bC1 : bC0)[r] = (_Float16)cv;
      (lvl ? bS1 : bS0)[r] = (_Float16)s;
    } else {  // w1 frags (pre-scaled by 0.1)
      int r0 = id - 8192;
      int lvl = r0 >> 12, r = r0 & 4095;
      int fi = r >> 9, lane = (r >> 3) & 63, j = r & 7;
      int ms = fi & 3, ks = fi >> 2;
      int h = ks * 32 + (lane >> 4) * 8 + j;
      int kout = ms * 16 + (lane & 15);
      const float* w = lvl ? c1w1 : c0w1;
      (lvl ? w1f1 : w1f0)[r] = (_Float16)(0.1f * w[h * HC + kout]);
    }
  } else {  // zero acc0|pooled|acc1: 147456 f32x4 over 192*256 threads
    int t = (blockIdx.x - 320) * 256 + threadIdx.x;  // 0..49151
    f32x4 z = {0.f, 0.f, 0.f, 0.f};
    f32x4* zp = (f32x4*)accz;
    zp[t] = z;
    zp[t + 49152] = z;
    zp[t + 98304] = z;
  }
}

// ---- k_conv: persistent edge-parallel, pipelined; accumulates via atomicAdd.
// L1 mode: t-row/d computed on demand from pooled (no tN1/dN1 precompute).
template <bool L1>
__global__ __launch_bounds__(256, 3) void k_conv(
    const int* __restrict__ ei, int E, int eTot,
    const float* __restrict__ posp,
    const float* __restrict__ tN, const float* __restrict__ dN,
    const unsigned* __restrict__ pooled, const int* __restrict__ keep,
    const float* __restrict__ w2, const float* __restrict__ b2,
    const float* __restrict__ kw0, const float* __restrict__ kb0,
    const _Float16* __restrict__ bC, const _Float16* __restrict__ bS,
    const _Float16* __restrict__ w1f, const float* __restrict__ b1,
    float* __restrict__ acc_out) {
  __shared__ __attribute__((aligned(16))) _Float16 bCs[4096], bSs[4096];
  __shared__ __attribute__((aligned(16))) _Float16 scS[4][2][64], scC[4][2][64];
  __shared__ float w2s[64][69];       // L1 only
  __shared__ float xrs[4][2][64];     // L1 only: staged x-row dbuf
  __shared__ float trow[4][64];       // L1 only: t-row redistribution
  const int tid = threadIdx.x;
  const int wave = __builtin_amdgcn_readfirstlane(tid >> 6), lane = tid & 63;
  const int q = lane >> 4;
  for (int idx = tid; idx < 512; idx += 256) {
    ((f16x8*)bCs)[idx] = ((const f16x8*)bC)[idx];
    ((f16x8*)bSs)[idx] = ((const f16x8*)bS)[idx];
  }
  if constexpr (L1) {
    for (int idx = tid; idx < HC * FC; idx += 256)
      w2s[idx / FC][idx % FC] = w2[idx];
  }
  f16x8 w1r[8];
#pragma unroll
  for (int f = 0; f < 8; ++f) w1r[f] = *(const f16x8*)(w1f + ((f << 6) + lane) * 8);
  f32x4 bbq[4];  // accumulator init = 0.1*b1[k]
#pragma unroll
  for (int ms = 0; ms < 4; ++ms) {
    f32x4 t = *(const f32x4*)(b1 + ms * 16 + q * 4);
    bbq[ms] = t * 0.1f;
  }
  const float kb0v = kb0[lane];
  const float kw0x = kw0[lane], kw0y = kw0[HC + lane], kw0z = kw0[2 * HC + lane];
  float b2v = 0.f, b2x = 0.f, b2y = 0.f, b2z = 0.f;
  if constexpr (L1) {
    b2v = b2[lane];
    b2x = b2[64]; b2y = b2[65]; b2z = b2[66];
  }
  __syncthreads();

  const int nW = gridDim.x * 4;
  int e = blockIdx.x * 4 + wave;
  if (e >= eTot) return;

  // Fast branchless trig: results feed sin(0.1*base) which is rounded to f16
  // (5e-4 rel ulp) -> poly errors (atan ~1e-7, asin ~7e-5 rad) are invisible.
  auto stg = [&](int ee, int bufIdx, int& sN, int& dTo, float& sv, float& cv,
                 float& dv, float& opx, float& opy, float& opz) {
    int s, d2;
    if (ee < E) { s = ei[ee]; d2 = ei[E + ee]; } else { s = ee - E; d2 = s; }
    sN = s;
    dTo = d2;
    const float px = posp[s * 3], py = posp[s * 3 + 1], pz = posp[s * 3 + 2];
    const float rx = posp[d2 * 3] - px;
    const float ry = posp[d2 * 3 + 1] - py;
    const float rz = posp[d2 * 3 + 2] - pz;
    opx = px; opy = py; opz = pz;
    float f0 = 0.f, f1 = 0.f, f2 = 0.f;
    if (!(rx == 0.f && ry == 0.f && rz == 0.f)) {
      const float INV_PI = 0.3183098861837907f;
      const float PI_F = 3.14159265358979f;
      const float PI_2 = 1.5707963267948966f;
      float rho = sqrtf(rx * rx + ry * ry + rz * rz);
      // theta = atan2(ry,rx): octant reduction + odd minimax poly on [0,1]
      float ax = fabsf(rx), ay = fabsf(ry);
      float mx = fmaxf(ax, ay), mn = fminf(ax, ay);
      float zr = mn * __builtin_amdgcn_rcpf(mx);
      float z2 = zr * zr;
      float pa = fmaf(z2, -0.0040540580f, 0.0218612288f);
      pa = fmaf(z2, pa, -0.0559098861f);
      pa = fmaf(z2, pa, 0.0964200441f);
      pa = fmaf(z2, pa, -0.1390853351f);
      pa = fmaf(z2, pa, 0.1994653599f);
      pa = fmaf(z2, pa, -0.3332985605f);
      pa = fmaf(z2, pa, 0.9999993329f);
      float at = pa * zr;
      at = (ay > ax) ? (PI_2 - at) : at;
      at = (rx < 0.f) ? (PI_F - at) : at;
      float th = copysignf(at, ry);
      // phi = asin(clip(rz/rho)): A&S 4.4.45, err <= 7e-5 rad
      float zz = rz * __builtin_amdgcn_rcpf(rho);
      float az = fminf(fabsf(zz), 1.0f);
      float sq = sqrtf(1.0f - az);
      float pp = fmaf(az, -0.0187293f, 0.0742610f);
      pp = fmaf(az, pp, -0.2121144f);
      pp = fmaf(az, pp, 1.5707288f);
      float as = PI_2 - sq * pp;
      float ph = copysignf(as, zz);
      f0 = rho; f1 = th * INV_PI; f2 = ph * INV_PI;
    }
    float base = fmaf(f0, kw0x, fmaf(f1, kw0y, fmaf(f2, kw0z, kb0v)));
    __sincosf(0.1f * base, &sv, &cv);
    if constexpr (L1) {
      // stage decoded pooled x-row + compute d on the fly
      int kn = keep[s];
      unsigned key = pooled[(size_t)kn * HC + lane];
      unsigned bb = (key & 0x80000000u) ? (key & 0x7FFFFFFFu) : ~key;
      float xv = __uint_as_float(bb);
      xrs[wave][bufIdx][lane] = xv;
      float dp = xv * b2v;
      dp += __shfl_xor(dp, 1, 64);  dp += __shfl_xor(dp, 2, 64);
      dp += __shfl_xor(dp, 4, 64);  dp += __shfl_xor(dp, 8, 64);
      dp += __shfl_xor(dp, 16, 64); dp += __shfl_xor(dp, 32, 64);
      dv = dp + fmaf(px, b2x, fmaf(py, b2y, pz * b2z));
    } else {
      dv = dN[s];
    }
  };

  int s0, d0;
  float sv0, cv0, dv0, p0x, p0y, p0z;
  stg(e, 0, s0, d0, sv0, cv0, dv0, p0x, p0y, p0z);
  int buf = 0;
  scS[wave][0][lane] = (_Float16)sv0;
  scC[wave][0][lane] = (_Float16)cv0;
  __builtin_amdgcn_wave_barrier();

  while (true) {
    const int en = e + nW;
    const bool more = en < eTot;
    // stage next edge (loads + trig) before compute of current
    int s1 = 0, d1 = 0;
    float sv1 = 0.f, cv1 = 0.f, dv1 = 0.f, p1x = 0.f, p1y = 0.f, p1z = 0.f;
    if (more) {
      stg(en, buf ^ 1, s1, d1, sv1, cv1, dv1, p1x, p1y, p1z);
      scS[wave][buf ^ 1][lane] = (_Float16)sv1;
      scC[wave][buf ^ 1][lane] = (_Float16)cv1;
    }
    __builtin_amdgcn_wave_barrier();

    // t-row for current edge
    f32x4 tr[4];
    if constexpr (L1) {
      float tl = 0.f;
#pragma unroll 8
      for (int f = 0; f < HC; ++f) tl = fmaf(xrs[wave][buf][f], w2s[lane][f], tl);
      tl = fmaf(p0x, w2s[lane][64],
           fmaf(p0y, w2s[lane][65], fmaf(p0z, w2s[lane][66], tl)));
      trow[wave][lane] = tl;
      __builtin_amdgcn_wave_barrier();
#pragma unroll
      for (int ms = 0; ms < 4; ++ms)
        tr[ms] = *(const f32x4*)&trow[wave][ms * 16 + q * 4];
      __builtin_amdgcn_wave_barrier();  // reads done before next overwrite
    } else {
      const float* trp = tN + (size_t)s0 * HC;
#pragma unroll
      for (int ms = 0; ms < 4; ++ms) tr[ms] = *(const f32x4*)(trp + ms * 16 + q * 4);
    }

    f32x4 acc[4][4];
#pragma unroll
    for (int ms = 0; ms < 4; ++ms)
#pragma unroll
      for (int nt = 0; nt < 4; ++nt) acc[ms][nt] = bbq[ms];
#pragma unroll
    for (int ks = 0; ks < 2; ++ks) {
      f16x8 sv8 = *(const f16x8*)&scS[wave][buf][ks * 32 + q * 8];
      f16x8 cv8 = *(const f16x8*)&scC[wave][buf][ks * 32 + q * 8];
      f16x8 bf[4];
#pragma unroll
      for (int nt = 0; nt < 4; ++nt) {
        f16x8 cb = *(const f16x8*)&bCs[((ks * 4 + nt) * 64 + lane) * 8];
        f16x8 sb = *(const f16x8*)&bSs[((ks * 4 + nt) * 64 + lane) * 8];
        bf[nt] = sv8 * cb + cv8 * sb;
      }
#pragma unroll
      for (int ms = 0; ms < 4; ++ms)
#pragma unroll
        for (int nt = 0; nt < 4; ++nt)
          acc[ms][nt] = __builtin_amdgcn_mfma_f32_16x16x32_f16(
              w1r[ks * 4 + ms], bf[nt], acc[ms][nt], 0, 0, 0);
    }

    // epilogue: reg r of acc[ms][nt] = 0.1*(z+b1) at [k=ms*16+q*4+r][c=nt*16+m]
    float snt0 = 0.f, snt1 = 0.f, snt2 = 0.f, snt3 = 0.f;
#pragma unroll
    for (int ms = 0; ms < 4; ++ms) {
#pragma unroll
      for (int r = 0; r < 4; ++r) {
        float tt = tr[ms][r];
        snt0 = fmaf(__sinf(acc[ms][0][r]), tt, snt0);
        snt1 = fmaf(__sinf(acc[ms][1][r]), tt, snt1);
        snt2 = fmaf(__sinf(acc[ms][2][r]), tt, snt2);
        snt3 = fmaf(__sinf(acc[ms][3][r]), tt, snt3);
      }
    }
    snt0 += __shfl_xor(snt0, 16, 64); snt0 += __shfl_xor(snt0, 32, 64);
    snt1 += __shfl_xor(snt1, 16, 64); snt1 += __shfl_xor(snt1, 32, 64);
    snt2 += __shfl_xor(snt2, 16, 64); snt2 += __shfl_xor(snt2, 32, 64);
    snt3 += __shfl_xor(snt3, 16, 64); snt3 += __shfl_xor(snt3, 32, 64);
    float val = (q == 0) ? snt0 : (q == 1) ? snt1 : (q == 2) ? snt2 : snt3;
    // direct scatter-accumulate: per-dst contention ~avg degree 5, acc is L2-resident
    atomicAdd(acc_out + (size_t)d0 * HC + lane, val + dv0);

    if (!more) break;
    e = en; s0 = s1; d0 = d1; dv0 = dv1;
    p0x = p1x; p0y = p1y; p0z = p1z;
    buf ^= 1;
  }
}

// ---- k_pool: edge-parallel max-pool of sin(0.01*(acc0[src]+bias)) into
//      per-NODE pooled buffer (order-preserving uint encoding; zeroed init:
//      every real value encodes >= 0x007FFFFF, every node has a self loop).
__global__ __launch_bounds__(256) void k_pool(
    const int* __restrict__ ei, const float* __restrict__ acc0,
    const float* __restrict__ bias, unsigned int* __restrict__ pooled) {
  const int wave = threadIdx.x >> 6, lane = threadIdx.x & 63;
  const float bz = bias[lane];
  for (int e = blockIdx.x * 4 + wave; e < E0T; e += gridDim.x * 4) {
    int s, d;
    if (e < E0C) { s = ei[e]; d = ei[E0C + e]; } else { s = e - E0C; d = s; }
    float v = sinf(0.01f * (acc0[(size_t)s * HC + lane] + bz));
    unsigned int b = __float_as_uint(v);
    unsigned int key = (b & 0x80000000u) ? ~b : (b | 0x80000000u);
    atomicMax(pooled + (size_t)d * HC + lane, key);
  }
}

// ---- k_final: sin(0.01*(acc1+bias)) + final linear + sin --------------------
__global__ __launch_bounds__(256) void k_final(
    const float* __restrict__ acc1, const float* __restrict__ bias,
    const float* __restrict__ l1w, const float* __restrict__ l1b,
    float* __restrict__ outp) {
  __shared__ float hr[4][64];
  const int wave = threadIdx.x >> 6, lane = threadIdx.x & 63;
  const int node = blockIdx.x * 4 + wave;
  hr[wave][lane] = sinf(0.01f * (acc1[(size_t)node * HC + lane] + bias[lane]));
  __syncthreads();
  if (lane < LATC) {
    const float* h = hr[wave];
    float o = l1b[lane];
#pragma unroll 8
    for (int c = 0; c < HC; ++c) o = fmaf(h[c], l1w[c * LATC + lane], o);
    outp[node * LATC + lane] = sinf(0.01f * o);
  }
}

extern "C" void kernel_launch(void* const* d_in, const int* in_sizes, int n_in,
                              void* d_out, int out_size, void* d_ws, size_t ws_size,
                              hipStream_t stream) {
  (void)in_sizes; (void)n_in; (void)out_size; (void)ws_size;
  const float* x    = (const float*)d_in[0];
  const float* pos  = (const float*)d_in[1];
  const int*   ei   = (const int*)d_in[2];
  const int*   pei  = (const int*)d_in[3];
  const float* ppos = (const float*)d_in[4];
  const int*   keep = (const int*)d_in[5];
  const float* l0w  = (const float*)d_in[6];
  const float* l0b  = (const float*)d_in[7];
  const float* l1w  = (const float*)d_in[8];
  const float* l1b  = (const float*)d_in[9];
  const float* c0w0 = (const float*)d_in[10];
  const float* c0b0 = (const float*)d_in[11];
  const float* c0w1 = (const float*)d_in[12];
  const float* c0b1 = (const float*)d_in[13];
  const float* c0w2 = (const float*)d_in[14];
  const float* c0b2 = (const float*)d_in[15];
  const float* c0bias = (const float*)d_in[16];
  const float* c1w0 = (const float*)d_in[17];
  const float* c1b0 = (const float*)d_in[18];
  const float* c1w1 = (const float*)d_in[19];
  const float* c1b1 = (const float*)d_in[20];
  const float* c1w2 = (const float*)d_in[21];
  const float* c1b2 = (const float*)d_in[22];
  const float* c1bias = (const float*)d_in[23];
  float* outp = (float*)d_out;

  char* p = (char*)d_ws;
  auto carve = [&](size_t bytes) -> char* {
    char* r = p;
    p += (bytes + 255) & ~(size_t)255;
    return r;
  };
  float* tN0  = (float*)carve((size_t)N0C * HC * 4);
  float* dN0  = (float*)carve((size_t)N0C * 4);
  _Float16* bC0  = (_Float16*)carve(4096 * 2);
  _Float16* bS0  = (_Float16*)carve(4096 * 2);
  _Float16* bC1  = (_Float16*)carve(4096 * 2);
  _Float16* bS1  = (_Float16*)carve(4096 * 2);
  _Float16* w1f0 = (_Float16*)carve(4096 * 2);
  _Float16* w1f1 = (_Float16*)carve(4096 * 2);
  // acc0 / pooled / acc1 contiguous (1MB | 1MB | 256KB): zeroed in k_prep
  float* acc0 = (float*)carve((size_t)N0C * HC * 4);
  unsigned int* pooled = (unsigned int*)carve((size_t)N0C * HC * 4);
  float* acc1 = (float*)carve((size_t)N1C * HC * 4);

  k_prep<<<512, 256, 0, stream>>>(x, l0w, l0b, pos, c0w2, c0b2,
                                  c0w0, c1w0, c0w1, c1w1,
                                  bC0, bS0, bC1, bS1, w1f0, w1f1,
                                  tN0, dN0, acc0);
  k_conv<false><<<768, 256, 0, stream>>>(ei, E0C, E0T, pos, tN0, dN0,
                                         nullptr, nullptr, nullptr, nullptr,
                                         c0w0, c0b0, bC0, bS0, w1f0, c0b1, acc0);
  k_pool<<<1280, 256, 0, stream>>>(ei, acc0, c0bias, pooled);
  k_conv<true><<<768, 256, 0, stream>>>(pei, E1C, E1T, ppos, nullptr, nullptr,
                                        pooled, keep, c1w2, c1b2,
                                        c1w0, c1b0, bC1, bS1, w1f1, c1b1, acc1);
  k_final<<<N1C / 4, 256, 0, stream>>>(acc1, c1bias, l1w, l1b, outp);
}